// Round 2
// baseline (85.969 us; speedup 1.0000x reference)
//
#include <hip/hip_runtime.h>
#include <hip/hip_bf16.h>
#include <stdint.h>

#define B_ 16
#define C_ 128
#define L_ 2048
#define LOG2E 1.4426950408889634f

typedef __attribute__((ext_vector_type(8))) short bf16x8;
typedef __attribute__((ext_vector_type(4))) float f32x4;
typedef __attribute__((ext_vector_type(16))) float f32x16;
typedef __attribute__((ext_vector_type(4))) unsigned int u32x4;

typedef __attribute__((address_space(3))) unsigned int lds_u32_t;
typedef const __attribute__((address_space(1))) unsigned int gbl_u32_t;

__device__ __forceinline__ void gload_lds16(const void* g, void* l) {
  // linear wave-uniform LDS dest (base + lane*16), per-lane global src
  __builtin_amdgcn_global_load_lds((gbl_u32_t*)g,
                                   (lds_u32_t*)(unsigned long long)l, 16, 0, 0);
}

__device__ __forceinline__ unsigned short f2bf(float x) {  // RNE f32->bf16
  union { float f; unsigned u; } v; v.f = x;
  unsigned u = v.u;
  u += 0x7fffu + ((u >> 16) & 1u);
  return (unsigned short)(u >> 16);
}

__device__ __forceinline__ unsigned pk2(float a, float b) {
  return (unsigned)f2bf(a) | ((unsigned)f2bf(b) << 16);
}

__device__ __forceinline__ unsigned cvtpk_bf16(float lo, float hi_) {
  unsigned r;
  asm("v_cvt_pk_bf16_f32 %0, %1, %2" : "=v"(r) : "v"(lo), "v"(hi_));
  return r;
}

__device__ __forceinline__ f32x16 z16() {
  f32x16 v;
#pragma unroll
  for (int i = 0; i < 16; ++i) v[i] = 0.f;
  return v;
}

__device__ __forceinline__ float tmax16(f32x16 v) {
  float a0 = fmaxf(v[0], v[1]),  a1 = fmaxf(v[2], v[3]);
  float a2 = fmaxf(v[4], v[5]),  a3 = fmaxf(v[6], v[7]);
  float a4 = fmaxf(v[8], v[9]),  a5 = fmaxf(v[10], v[11]);
  float a6 = fmaxf(v[12], v[13]), a7 = fmaxf(v[14], v[15]);
  float b0 = fmaxf(a0, a1), b1 = fmaxf(a2, a3);
  float b2 = fmaxf(a4, a5), b3 = fmaxf(a6, a7);
  return fmaxf(fmaxf(b0, b1), fmaxf(b2, b3));
}

__device__ __forceinline__ float tsum16(f32x16 v) {
  float a0 = v[0] + v[1],  a1 = v[2] + v[3];
  float a2 = v[4] + v[5],  a3 = v[6] + v[7];
  float a4 = v[8] + v[9],  a5 = v[10] + v[11];
  float a6 = v[12] + v[13], a7 = v[14] + v[15];
  float b0 = a0 + a1, b1 = a2 + a3, b2 = a4 + a5, b3 = a6 + a7;
  return (b0 + b1) + (b2 + b3);
}

// ---------------------------------------------------------------------------
// Projection: Q[b,l,o] = (sum_c x[b,c,l]*W1[o,c] + b1[o]) * log2(e)  (bf16,[B][L][C])
//             K same with W2/b2 (unscaled); V transposed Vt[b,o,l] ([B][C][L])
// ---------------------------------------------------------------------------
__global__ __launch_bounds__(256, 2) void proj_kernel(
    const float* __restrict__ x,
    const float* __restrict__ W1, const float* __restrict__ b1,
    const float* __restrict__ W2, const float* __restrict__ b2,
    const float* __restrict__ W3, const float* __restrict__ b3,
    unsigned short* __restrict__ Qo, unsigned short* __restrict__ Ko,
    unsigned short* __restrict__ Vt)
{
  __shared__ unsigned short Xt[64][136];   // [l_local][c], pad 136 breaks conflicts
  __shared__ unsigned short Wl[128][136];  // [o][c]

  const int b  = blockIdx.x & 15;
  const int lt = blockIdx.x >> 4;          // 0..31
  const int l0 = lt * 64;
  const int tid = threadIdx.x;
  const int w = tid >> 6, lane = tid & 63, li = lane & 15, lg = lane >> 4;

  // stage X tile: x[b][c][l0..l0+63] -> Xt[l][c] (bf16)
  for (int it = 0; it < 8; ++it) {
    int idx = tid + it * 256;              // 0..2047
    int c = idx >> 4, f4 = idx & 15;
    const float4 vv = *(const float4*)(x + (size_t)(b * C_ + c) * L_ + l0 + f4 * 4);
    Xt[f4 * 4 + 0][c] = f2bf(vv.x);
    Xt[f4 * 4 + 1][c] = f2bf(vv.y);
    Xt[f4 * 4 + 2][c] = f2bf(vv.z);
    Xt[f4 * 4 + 3][c] = f2bf(vv.w);
  }

  auto stageW = [&](const float* W) {
    for (int it = 0; it < 16; ++it) {
      int idx = tid + it * 256;            // 0..4095
      int o = idx >> 5, f4 = idx & 31;
      const float4 vv = *(const float4*)(W + (size_t)o * C_ + f4 * 4);
      unsigned short* p = &Wl[o][f4 * 4];
      p[0] = f2bf(vv.x); p[1] = f2bf(vv.y); p[2] = f2bf(vv.z); p[3] = f2bf(vv.w);
    }
  };

  // mode 0: write [B][L][C] (Q/K), scaled by sc. mode 1: write transposed Vt.
  auto computePhase = [&](const float* bias, unsigned short* Out, int mode, float sc) {
    f32x4 acc[8];
#pragma unroll
    for (int ni = 0; ni < 8; ++ni) acc[ni] = (f32x4){0.f, 0.f, 0.f, 0.f};
    bf16x8 af[4];
#pragma unroll
    for (int kk = 0; kk < 4; ++kk)
      af[kk] = *(const bf16x8*)&Xt[w * 16 + li][lg * 8 + kk * 32];
#pragma unroll
    for (int kk = 0; kk < 4; ++kk) {
#pragma unroll
      for (int ni = 0; ni < 8; ++ni) {
        bf16x8 bf = *(const bf16x8*)&Wl[ni * 16 + li][lg * 8 + kk * 32];
        acc[ni] = __builtin_amdgcn_mfma_f32_16x16x32_bf16(af[kk], bf, acc[ni], 0, 0, 0);
      }
    }
    if (mode == 0) {
#pragma unroll
      for (int ni = 0; ni < 8; ++ni) {
        float bv = bias[ni * 16 + li];
#pragma unroll
        for (int r = 0; r < 4; ++r) {
          int lrow = l0 + w * 16 + lg * 4 + r;
          Out[(size_t)(b * L_ + lrow) * C_ + ni * 16 + li] = f2bf((acc[ni][r] + bv) * sc);
        }
      }
    } else {
#pragma unroll
      for (int ni = 0; ni < 8; ++ni) {
        float bv = bias[ni * 16 + li];
        int o = ni * 16 + li;
        unsigned long long pw =
            (unsigned long long)pk2(acc[ni][0] + bv, acc[ni][1] + bv) |
            ((unsigned long long)pk2(acc[ni][2] + bv, acc[ni][3] + bv) << 32);
        *(unsigned long long*)(Out + (size_t)(b * C_ + o) * L_ + l0 + w * 16 + lg * 4) = pw;
      }
    }
  };

  stageW(W1);
  __syncthreads();
  computePhase(b1, Qo, 0, LOG2E);   // Q pre-scaled: scores land in log2-domain
  __syncthreads();
  stageW(W2);
  __syncthreads();
  computePhase(b2, Ko, 0, 1.0f);
  __syncthreads();
  stageW(W3);
  __syncthreads();
  computePhase(b3, Vt, 1, 1.0f);
}

// ---------------------------------------------------------------------------
// Flash attention, 32x32x16 MFMA. Block = (batch, 128 q-rows), 4 waves x 32 q.
// S^T = mfma(K, Q): lane owns q-col = lane&31; 32 scores/lane (16 + partner 16).
// Softmax fully in-register (exp2 domain, defer-max THR=8). P assembled into
// B-frags via 2 shfl_xor(32)+selects per 16-j block. O^T = mfma(Vt, P).
// K/V staged via global_load_lds (linear dest, pre-swizzled src, XOR-swz reads).
// ---------------------------------------------------------------------------
__global__ __launch_bounds__(256, 1) void attn_kernel(
    const unsigned short* __restrict__ Q,
    const unsigned short* __restrict__ K,
    const unsigned short* __restrict__ Vt,
    float* __restrict__ out)
{
  __shared__ unsigned short kbuf[2][64 * C_];   // [j][c], rows 256B, swizzled
  __shared__ unsigned short vbuf[2][C_ * 64];   // [c][j], rows 128B, swizzled

  const int b  = blockIdx.x & 15;               // batch b -> XCD b&7 (L2-resident K/V)
  const int qt = blockIdx.x >> 4;
  const int tid = threadIdx.x;
  const int w = tid >> 6, lane = tid & 63;
  const int q32 = lane & 31, hi = lane >> 5;
  const int qrow = qt * 128 + w * 32 + q32;
  const size_t bLC = (size_t)b * L_ * C_;

  // Q B-frags: lane holds Q[qrow][kt*16 + hi*8 .. +7]
  bf16x8 qf[8];
  {
    const unsigned short* qp = Q + bLC + (size_t)qrow * C_ + hi * 8;
#pragma unroll
    for (int kt = 0; kt < 8; ++kt) qf[kt] = *(const bf16x8*)(qp + kt * 16);
  }

  f32x16 oacc[4];
#pragma unroll
  for (int i = 0; i < 4; ++i) oacc[i] = z16();
  float m2 = -3e38f, lrun = 0.f;                // running max in log2 units

  const char* kgb = (const char*)(K + bLC);
  const char* vgb = (const char*)(Vt + bLC);

  auto stage = [&](int sel, int t) {
    const char* ktb = kgb + (size_t)t * (64 * 256);   // K tile (16KB)
    const char* vt0 = vgb + (size_t)t * 128;          // V tile col-byte offset
#pragma unroll
    for (int i2 = 0; i2 < 4; ++i2) {
      int db = w * 4096 + i2 * 1024;                  // wave-uniform chunk
      int d  = db + lane * 16;
      int row = d >> 8, cb = d & 255;                 // K: 256B rows
      gload_lds16(ktb + row * 256 + (cb ^ ((row & 7) << 4)), (char*)kbuf[sel] + db);
      int rc = d >> 7, cv = d & 127;                  // V: 128B rows
      gload_lds16(vt0 + (size_t)rc * (L_ * 2) + (cv ^ ((rc & 7) << 4)),
                  (char*)vbuf[sel] + db);
    }
  };

  stage(0, 0);
  __syncthreads();

  int cur = 0;
  for (int t = 0; t < 32; ++t) {
    if (t + 1 < 32) stage(cur ^ 1, t + 1);

    // ---- QK^T: S^T[j, q] ; s0 = j 0..31, s1 = j 32..63 (lane holds 16 each)
    const char* kb = (const char*)kbuf[cur];
    f32x16 s0 = z16(), s1 = z16();
#pragma unroll
    for (int kt2 = 0; kt2 < 8; ++kt2) {
      int row0 = q32, row1 = 32 + q32;
      bf16x8 kf0 = *(const bf16x8*)(kb + (row0 << 8) +
                                    ((kt2 * 32 + hi * 16) ^ ((row0 & 7) << 4)));
      bf16x8 kf1 = *(const bf16x8*)(kb + (row1 << 8) +
                                    ((kt2 * 32 + hi * 16) ^ ((row1 & 7) << 4)));
      s0 = __builtin_amdgcn_mfma_f32_32x32x16_bf16(kf0, qf[kt2], s0, 0, 0, 0);
      s1 = __builtin_amdgcn_mfma_f32_32x32x16_bf16(kf1, qf[kt2], s1, 0, 0, 0);
    }

    // ---- online softmax (log2 domain; scores pre-scaled by log2e)
    float pm = fmaxf(tmax16(s0), tmax16(s1));
    pm = fmaxf(pm, __shfl_xor(pm, 32));
    if (!__all(pm - m2 <= 8.f)) {                    // defer-max (T13)
      float mn = fmaxf(m2, pm);
      float al = exp2f(m2 - mn);
      lrun *= al;
#pragma unroll
      for (int ct = 0; ct < 4; ++ct) oacc[ct] = oacc[ct] * al;
      m2 = mn;
    }
#pragma unroll
    for (int r = 0; r < 16; ++r) {
      s0[r] = exp2f(s0[r] - m2);
      s1[r] = exp2f(s1[r] - m2);
    }
    float ps = tsum16(s0) + tsum16(s1);
    ps += __shfl_xor(ps, 32);
    lrun += ps;

    // ---- PV: O^T[c, q] += Vt_tile * P   (P assembled in-register)
    const char* vb = (const char*)vbuf[cur];
    auto pvstep = [&](const f32x16& sv, int kj) {
      const int base = (kj & 1) * 8;
      // lane owns j with bit2 == hi within each 8-block of its jt half.
      unsigned wl0 = cvtpk_bf16(sv[base + 0], sv[base + 1]);  // j kt16 + 4h + {0,1}
      unsigned wl1 = cvtpk_bf16(sv[base + 2], sv[base + 3]);  // j kt16 + 4h + {2,3}
      unsigned wh0 = cvtpk_bf16(sv[base + 4], sv[base + 5]);  // j kt16 + 8 + 4h + {0,1}
      unsigned wh1 = cvtpk_bf16(sv[base + 6], sv[base + 7]);
      // exchange with lane^32 partner (same q-col): h0 sends hi-words, h1 sends lo-words
      unsigned snd0 = hi ? wl0 : wh0;
      unsigned snd1 = hi ? wl1 : wh1;
      unsigned rcv0 = (unsigned)__shfl_xor((int)snd0, 32);
      unsigned rcv1 = (unsigned)__shfl_xor((int)snd1, 32);
      unsigned w0 = hi ? rcv0 : wl0;   // j kt16 + hi*8 + {0,1}
      unsigned w1 = hi ? rcv1 : wl1;
      unsigned w2 = hi ? wh0 : rcv0;   // j kt16 + hi*8 + {4,5}
      unsigned w3 = hi ? wh1 : rcv1;
      u32x4 pw = {w0, w1, w2, w3};
      bf16x8 pf = *reinterpret_cast<bf16x8*>(&pw);
#pragma unroll
      for (int ct = 0; ct < 4; ++ct) {
        int rowc = ct * 32 + q32;
        bf16x8 vf = *(const bf16x8*)(vb + (rowc << 7) +
                                     ((kj * 32 + hi * 16) ^ ((rowc & 7) << 4)));
        oacc[ct] = __builtin_amdgcn_mfma_f32_32x32x16_bf16(vf, pf, oacc[ct], 0, 0, 0);
      }
    };
    pvstep(s0, 0);
    pvstep(s0, 1);
    pvstep(s1, 2);
    pvstep(s1, 3);

    __syncthreads();
    cur ^= 1;
  }

  // ---- epilogue: out[b][c][l=qrow] = O^T[c][q] / l_q
  float inv = 1.0f / lrun;
  float* ob = out + (size_t)b * C_ * L_ + qrow;
#pragma unroll
  for (int ct = 0; ct < 4; ++ct) {
#pragma unroll
    for (int r = 0; r < 16; ++r) {
      int c = ct * 32 + (r & 3) + 8 * (r >> 2) + 4 * hi;
      ob[(size_t)c * L_] = oacc[ct][r] * inv;
    }
  }
}

extern "C" void kernel_launch(void* const* d_in, const int* in_sizes, int n_in,
                              void* d_out, int out_size, void* d_ws, size_t ws_size,
                              hipStream_t stream) {
  (void)in_sizes; (void)n_in; (void)out_size; (void)ws_size;
  const float* x  = (const float*)d_in[0];
  const float* W1 = (const float*)d_in[1];
  const float* b1 = (const float*)d_in[2];
  const float* W2 = (const float*)d_in[3];
  const float* b2 = (const float*)d_in[4];
  const float* W3 = (const float*)d_in[5];
  const float* b3 = (const float*)d_in[6];

  unsigned short* Q  = (unsigned short*)d_ws;              // [B][L][C] bf16 (x log2e)
  unsigned short* K  = Q + (size_t)B_ * L_ * C_;           // [B][L][C] bf16
  unsigned short* Vt = K + (size_t)B_ * L_ * C_;           // [B][C][L] bf16

  proj_kernel<<<512, 256, 0, stream>>>(x, W1, b1, W2, b2, W3, b3, Q, K, Vt);
  attn_kernel<<<256, 256, 0, stream>>>(Q, K, Vt, (float*)d_out);
}

// Round 3
// 74.717 us; speedup vs baseline: 1.1506x; 1.1506x over previous
//
#include <hip/hip_runtime.h>
#include <hip/hip_bf16.h>
#include <stdint.h>

#define B_ 16
#define C_ 128
#define L_ 2048
#define LOG2E 1.4426950408889634f

typedef __attribute__((ext_vector_type(8))) short bf16x8;
typedef __attribute__((ext_vector_type(4))) float f32x4;
typedef __attribute__((ext_vector_type(16))) float f32x16;
typedef __attribute__((ext_vector_type(4))) unsigned int u32x4;

typedef __attribute__((address_space(3))) unsigned int lds_u32_t;
typedef const __attribute__((address_space(1))) unsigned int gbl_u32_t;

__device__ __forceinline__ void gload_lds16(const void* g, void* l) {
  // linear wave-uniform LDS dest (base + lane*16), per-lane global src
  __builtin_amdgcn_global_load_lds((gbl_u32_t*)g,
                                   (lds_u32_t*)(unsigned long long)l, 16, 0, 0);
}

__device__ __forceinline__ unsigned short f2bf(float x) {  // RNE f32->bf16
  union { float f; unsigned u; } v; v.f = x;
  unsigned u = v.u;
  u += 0x7fffu + ((u >> 16) & 1u);
  return (unsigned short)(u >> 16);
}

__device__ __forceinline__ unsigned pk2(float a, float b) {
  return (unsigned)f2bf(a) | ((unsigned)f2bf(b) << 16);
}

__device__ __forceinline__ unsigned cvtpk_bf16(float lo, float hi_) {
  unsigned r;
  asm("v_cvt_pk_bf16_f32 %0, %1, %2" : "=v"(r) : "v"(lo), "v"(hi_));
  return r;
}

__device__ __forceinline__ f32x16 z16() {
  f32x16 v;
#pragma unroll
  for (int i = 0; i < 16; ++i) v[i] = 0.f;
  return v;
}

__device__ __forceinline__ float tmax16(const f32x16& v) {
  float a0 = fmaxf(v[0], v[1]),  a1 = fmaxf(v[2], v[3]);
  float a2 = fmaxf(v[4], v[5]),  a3 = fmaxf(v[6], v[7]);
  float a4 = fmaxf(v[8], v[9]),  a5 = fmaxf(v[10], v[11]);
  float a6 = fmaxf(v[12], v[13]), a7 = fmaxf(v[14], v[15]);
  float b0 = fmaxf(a0, a1), b1 = fmaxf(a2, a3);
  float b2 = fmaxf(a4, a5), b3 = fmaxf(a6, a7);
  return fmaxf(fmaxf(b0, b1), fmaxf(b2, b3));
}

__device__ __forceinline__ float tsum16(const f32x16& v) {
  float a0 = v[0] + v[1],  a1 = v[2] + v[3];
  float a2 = v[4] + v[5],  a3 = v[6] + v[7];
  float a4 = v[8] + v[9],  a5 = v[10] + v[11];
  float a6 = v[12] + v[13], a7 = v[14] + v[15];
  float b0 = a0 + a1, b1 = a2 + a3, b2 = a4 + a5, b3 = a6 + a7;
  return (b0 + b1) + (b2 + b3);
}

// ---------------------------------------------------------------------------
// Projection: Q[b,l,o] = (sum_c x[b,c,l]*W1[o,c] + b1[o]) * log2(e)  (bf16,[B][L][C])
//             K same with W2/b2 (unscaled); V transposed Vt[b,o,l] ([B][C][L])
// ---------------------------------------------------------------------------
__global__ __launch_bounds__(256, 2) void proj_kernel(
    const float* __restrict__ x,
    const float* __restrict__ W1, const float* __restrict__ b1,
    const float* __restrict__ W2, const float* __restrict__ b2,
    const float* __restrict__ W3, const float* __restrict__ b3,
    unsigned short* __restrict__ Qo, unsigned short* __restrict__ Ko,
    unsigned short* __restrict__ Vt)
{
  __shared__ unsigned short Xt[64][136];   // [l_local][c], pad 136 breaks conflicts
  __shared__ unsigned short Wl[128][136];  // [o][c]

  const int b  = blockIdx.x & 15;
  const int lt = blockIdx.x >> 4;          // 0..31
  const int l0 = lt * 64;
  const int tid = threadIdx.x;
  const int w = tid >> 6, lane = tid & 63, li = lane & 15, lg = lane >> 4;

  // stage X tile: x[b][c][l0..l0+63] -> Xt[l][c] (bf16)
  for (int it = 0; it < 8; ++it) {
    int idx = tid + it * 256;              // 0..2047
    int c = idx >> 4, f4 = idx & 15;
    const float4 vv = *(const float4*)(x + (size_t)(b * C_ + c) * L_ + l0 + f4 * 4);
    Xt[f4 * 4 + 0][c] = f2bf(vv.x);
    Xt[f4 * 4 + 1][c] = f2bf(vv.y);
    Xt[f4 * 4 + 2][c] = f2bf(vv.z);
    Xt[f4 * 4 + 3][c] = f2bf(vv.w);
  }

  auto stageW = [&](const float* W) {
    for (int it = 0; it < 16; ++it) {
      int idx = tid + it * 256;            // 0..4095
      int o = idx >> 5, f4 = idx & 31;
      const float4 vv = *(const float4*)(W + (size_t)o * C_ + f4 * 4);
      unsigned short* p = &Wl[o][f4 * 4];
      p[0] = f2bf(vv.x); p[1] = f2bf(vv.y); p[2] = f2bf(vv.z); p[3] = f2bf(vv.w);
    }
  };

  // mode 0: write [B][L][C] (Q/K), scaled by sc. mode 1: write transposed Vt.
  auto computePhase = [&](const float* bias, unsigned short* Out, int mode, float sc) {
    f32x4 acc[8];
#pragma unroll
    for (int ni = 0; ni < 8; ++ni) acc[ni] = (f32x4){0.f, 0.f, 0.f, 0.f};
    bf16x8 af[4];
#pragma unroll
    for (int kk = 0; kk < 4; ++kk)
      af[kk] = *(const bf16x8*)&Xt[w * 16 + li][lg * 8 + kk * 32];
#pragma unroll
    for (int kk = 0; kk < 4; ++kk) {
#pragma unroll
      for (int ni = 0; ni < 8; ++ni) {
        bf16x8 bf = *(const bf16x8*)&Wl[ni * 16 + li][lg * 8 + kk * 32];
        acc[ni] = __builtin_amdgcn_mfma_f32_16x16x32_bf16(af[kk], bf, acc[ni], 0, 0, 0);
      }
    }
    if (mode == 0) {
#pragma unroll
      for (int ni = 0; ni < 8; ++ni) {
        float bv = bias[ni * 16 + li];
#pragma unroll
        for (int r = 0; r < 4; ++r) {
          int lrow = l0 + w * 16 + lg * 4 + r;
          Out[(size_t)(b * L_ + lrow) * C_ + ni * 16 + li] = f2bf((acc[ni][r] + bv) * sc);
        }
      }
    } else {
#pragma unroll
      for (int ni = 0; ni < 8; ++ni) {
        float bv = bias[ni * 16 + li];
        int o = ni * 16 + li;
        unsigned long long pw =
            (unsigned long long)pk2(acc[ni][0] + bv, acc[ni][1] + bv) |
            ((unsigned long long)pk2(acc[ni][2] + bv, acc[ni][3] + bv) << 32);
        *(unsigned long long*)(Out + (size_t)(b * C_ + o) * L_ + l0 + w * 16 + lg * 4) = pw;
      }
    }
  };

  stageW(W1);
  __syncthreads();
  computePhase(b1, Qo, 0, LOG2E);   // Q pre-scaled: scores land in log2-domain
  __syncthreads();
  stageW(W2);
  __syncthreads();
  computePhase(b2, Ko, 0, 1.0f);
  __syncthreads();
  stageW(W3);
  __syncthreads();
  computePhase(b3, Vt, 1, 1.0f);
}

// ---------------------------------------------------------------------------
// Flash attention, 32x32x16 MFMA. Block = (batch, 128 q-rows), 8 waves paired:
// wave (qg, jh): 32 q-rows (qg), half of every KV tile's j-range (jh).
// Each wave runs an independent online softmax over its disjoint KV subset;
// pairs combine (m, l, O) exactly through reused staging LDS at the end.
// K/V staged via global_load_lds (linear dest, pre-swizzled src, XOR-swz reads).
// K tile rows 256B -> swizzle (row&15)<<4 (2-way, free). V rows 128B -> (row&7)<<4.
// ---------------------------------------------------------------------------
__global__ __launch_bounds__(512, 2) void attn_kernel(
    const unsigned short* __restrict__ Q,
    const unsigned short* __restrict__ K,
    const unsigned short* __restrict__ Vt,
    float* __restrict__ out)
{
  __shared__ char smem[65536 + 2048];  // [0,32K)=K dbuf, [32K,64K)=V dbuf, +2K ml

  const int b  = blockIdx.x & 15;               // batch -> XCD (L2-resident K/V)
  const int qt = blockIdx.x >> 4;
  const int tid = threadIdx.x;
  const int w = tid >> 6, lane = tid & 63;
  const int q32 = lane & 31, hi = lane >> 5;
  const int qg = w >> 1, jh = w & 1;
  const int qrow = qt * 128 + qg * 32 + q32;
  const size_t bLC = (size_t)b * L_ * C_;

  // Q B-frags: lane holds Q[qrow][kt*16 + hi*8 .. +7]
  bf16x8 qf[8];
  {
    const unsigned short* qp = Q + bLC + (size_t)qrow * C_ + hi * 8;
#pragma unroll
    for (int kt = 0; kt < 8; ++kt) qf[kt] = *(const bf16x8*)(qp + kt * 16);
  }

  f32x16 oacc[4];
#pragma unroll
  for (int i = 0; i < 4; ++i) oacc[i] = z16();
  float m2 = -3e38f, lrun = 0.f;                // running max in log2 units

  const char* kgb = (const char*)(K + bLC);
  const char* vgb = (const char*)(Vt + bLC);

  // waves 0..3 stage K (16KB), waves 4..7 stage V (16KB); 4 gload_lds each
  auto stage = [&](int sel, int t) {
    if (w < 4) {
      const char* ktb = kgb + (size_t)t * (64 * 256);
      char* dst = smem + sel * 16384 + (w & 3) * 4096;
#pragma unroll
      for (int i2 = 0; i2 < 4; ++i2) {
        int d = (w & 3) * 4096 + i2 * 1024 + lane * 16;
        int row = d >> 8, cb = d & 255;
        gload_lds16(ktb + row * 256 + (cb ^ ((row & 15) << 4)), dst + i2 * 1024);
      }
    } else {
      const char* vt0 = vgb + (size_t)t * 128;
      char* dst = smem + 32768 + sel * 16384 + (w & 3) * 4096;
#pragma unroll
      for (int i2 = 0; i2 < 4; ++i2) {
        int d = (w & 3) * 4096 + i2 * 1024 + lane * 16;
        int rc = d >> 7, cv = d & 127;
        gload_lds16(vt0 + (size_t)rc * (L_ * 2) + (cv ^ ((rc & 7) << 4)), dst + i2 * 1024);
      }
    }
  };

  stage(0, 0);
  __syncthreads();

  int cur = 0;
  for (int t = 0; t < 32; ++t) {
    if (t + 1 < 32) stage(cur ^ 1, t + 1);

    // ---- QK^T: this wave's j-half. Two 4-deep MFMA chains for ILP.
    const char* kb = smem + cur * 16384;
    const int krow = jh * 32 + q32;
    const int kro  = krow << 8, ksw = (krow & 15) << 4;
    f32x16 sA = z16(), sB = z16();
    __builtin_amdgcn_s_setprio(1);
#pragma unroll
    for (int kt2 = 0; kt2 < 4; ++kt2) {
      bf16x8 kf0 = *(const bf16x8*)(kb + kro + ((kt2 * 32 + hi * 16) ^ ksw));
      bf16x8 kf1 = *(const bf16x8*)(kb + kro + (((kt2 + 4) * 32 + hi * 16) ^ ksw));
      sA = __builtin_amdgcn_mfma_f32_32x32x16_bf16(kf0, qf[kt2], sA, 0, 0, 0);
      sB = __builtin_amdgcn_mfma_f32_32x32x16_bf16(kf1, qf[kt2 + 4], sB, 0, 0, 0);
    }
    __builtin_amdgcn_s_setprio(0);
    f32x16 s;
#pragma unroll
    for (int r = 0; r < 16; ++r) s[r] = sA[r] + sB[r];

    // ---- online softmax over this wave's 32 j (log2 domain, defer-max THR=8)
    float pm = tmax16(s);
    pm = fmaxf(pm, __shfl_xor(pm, 32));
    if (!__all(pm - m2 <= 8.f)) {
      float mn = fmaxf(m2, pm);
      float al = exp2f(m2 - mn);
      lrun *= al;
#pragma unroll
      for (int ct = 0; ct < 4; ++ct) oacc[ct] = oacc[ct] * al;
      m2 = mn;
    }
#pragma unroll
    for (int r = 0; r < 16; ++r) s[r] = exp2f(s[r] - m2);
    float ps = tsum16(s);
    ps += __shfl_xor(ps, 32);
    lrun += ps;

    // ---- assemble both P frags (j_local kj*16 + hi*8 + 0..7) in-register
    bf16x8 pf[2];
#pragma unroll
    for (int kj = 0; kj < 2; ++kj) {
      const int base = kj * 8;
      unsigned wl0 = cvtpk_bf16(s[base + 0], s[base + 1]);
      unsigned wl1 = cvtpk_bf16(s[base + 2], s[base + 3]);
      unsigned wh0 = cvtpk_bf16(s[base + 4], s[base + 5]);
      unsigned wh1 = cvtpk_bf16(s[base + 6], s[base + 7]);
      unsigned snd0 = hi ? wl0 : wh0;
      unsigned snd1 = hi ? wl1 : wh1;
      unsigned rcv0 = (unsigned)__shfl_xor((int)snd0, 32);
      unsigned rcv1 = (unsigned)__shfl_xor((int)snd1, 32);
      unsigned w0 = hi ? rcv0 : wl0;
      unsigned w1 = hi ? rcv1 : wl1;
      unsigned w2 = hi ? wh0 : rcv0;
      unsigned w3 = hi ? wh1 : rcv1;
      u32x4 pw = {w0, w1, w2, w3};
      pf[kj] = *reinterpret_cast<bf16x8*>(&pw);
    }

    // ---- PV: O^T[c, q] += Vt_tile[:, jh-half] * P
    const char* vb = smem + 32768 + cur * 16384;
    __builtin_amdgcn_s_setprio(1);
#pragma unroll
    for (int kj = 0; kj < 2; ++kj) {
      const int kjg = jh * 2 + kj;
#pragma unroll
      for (int ct = 0; ct < 4; ++ct) {
        int rowc = ct * 32 + q32;
        bf16x8 vf = *(const bf16x8*)(vb + (rowc << 7) +
                                     ((kjg * 32 + hi * 16) ^ ((rowc & 7) << 4)));
        oacc[ct] = __builtin_amdgcn_mfma_f32_32x32x16_bf16(vf, pf[kj], oacc[ct], 0, 0, 0);
      }
    }
    __builtin_amdgcn_s_setprio(0);

    __syncthreads();
    cur ^= 1;
  }

  // ---- pair combine: (qg, jh=0) merges (qg, jh=1)'s partial (m, l, O) exactly
  float* mlb = (float*)(smem + 65536);          // [8 waves][32 q][2]
  if (hi == 0) {
    mlb[(w * 32 + q32) * 2 + 0] = m2;
    mlb[(w * 32 + q32) * 2 + 1] = lrun;
  }
  __syncthreads();
  const float mB = mlb[((w ^ 1) * 32 + q32) * 2 + 0];
  const float lB = mlb[((w ^ 1) * 32 + q32) * 2 + 1];
  const float mstar = fmaxf(m2, mB);
  const float aown  = exp2f(m2 - mstar);
  float* scrb = (float*)smem + (size_t)(qg * 64 + lane) * 33;  // pad-33: conflict-free
  float* ob = out + (size_t)b * C_ * L_ + qrow;
  float inv = 0.f;
  if (jh == 0) {
    const float aB = exp2f(mB - mstar);
    inv = 1.0f / (lrun * aown + lB * aB);
  }
  __syncthreads();
  if (jh == 1) {
#pragma unroll
    for (int r = 0; r < 16; ++r) {
      scrb[r]      = oacc[0][r] * aown;
      scrb[16 + r] = oacc[1][r] * aown;
    }
  }
  __syncthreads();
  if (jh == 0) {
#pragma unroll
    for (int ct = 0; ct < 2; ++ct)
#pragma unroll
      for (int r = 0; r < 16; ++r) {
        float v = oacc[ct][r] * aown + scrb[ct * 16 + r];
        int c = ct * 32 + (r & 3) + 8 * (r >> 2) + 4 * hi;
        ob[(size_t)c * L_] = v * inv;
      }
  }
  __syncthreads();
  if (jh == 1) {
#pragma unroll
    for (int r = 0; r < 16; ++r) {
      scrb[r]      = oacc[2][r] * aown;
      scrb[16 + r] = oacc[3][r] * aown;
    }
  }
  __syncthreads();
  if (jh == 0) {
#pragma unroll
    for (int ct = 0; ct < 2; ++ct)
#pragma unroll
      for (int r = 0; r < 16; ++r) {
        float v = oacc[2 + ct][r] * aown + scrb[ct * 16 + r];
        int c = (2 + ct) * 32 + (r & 3) + 8 * (r >> 2) + 4 * hi;
        ob[(size_t)c * L_] = v * inv;
      }
  }
}

extern "C" void kernel_launch(void* const* d_in, const int* in_sizes, int n_in,
                              void* d_out, int out_size, void* d_ws, size_t ws_size,
                              hipStream_t stream) {
  (void)in_sizes; (void)n_in; (void)out_size; (void)ws_size;
  const float* x  = (const float*)d_in[0];
  const float* W1 = (const float*)d_in[1];
  const float* b1 = (const float*)d_in[2];
  const float* W2 = (const float*)d_in[3];
  const float* b2 = (const float*)d_in[4];
  const float* W3 = (const float*)d_in[5];
  const float* b3 = (const float*)d_in[6];

  unsigned short* Q  = (unsigned short*)d_ws;              // [B][L][C] bf16 (x log2e)
  unsigned short* K  = Q + (size_t)B_ * L_ * C_;           // [B][L][C] bf16
  unsigned short* Vt = K + (size_t)B_ * L_ * C_;           // [B][C][L] bf16

  proj_kernel<<<512, 256, 0, stream>>>(x, W1, b1, W2, b2, W3, b3, Q, K, Vt);
  attn_kernel<<<256, 512, 0, stream>>>(Q, K, Vt, (float*)d_out);
}